// Round 2
// baseline (299.357 us; speedup 1.0000x reference)
//
#include <hip/hip_runtime.h>

#define NB 8192
#define ND 256
#define NH 512
#define NO 64
#define NK 8
#define TB 16   // rows per tile

// ws int layout: [0..8) counts | [8..16) cursor | [16..16+NB) idx | [16+NB..16+2NB) perm

__global__ __launch_bounds__(256) void router_count(const float* __restrict__ x,
                                                    int* __restrict__ wsI) {
    __shared__ int lc[NK];
    const int t = threadIdx.x;
    if (t < NK) lc[t] = 0;
    __syncthreads();
    const int b = blockIdx.x * 256 + t;
    const float v = x[(size_t)b * ND + 7];
    const int e = ((int)fabsf(v * 100.0f)) & (NK - 1);   // matches abs().astype(int32) % 8
    wsI[16 + b] = e;
    atomicAdd(&lc[e], 1);
    __syncthreads();
    if (t < NK) atomicAdd(&wsI[t], lc[t]);
}

__global__ void scan8(int* __restrict__ wsI) {
    if (threadIdx.x == 0 && blockIdx.x == 0) {
        int s = 0;
#pragma unroll
        for (int k = 0; k < NK; k++) { wsI[8 + k] = s; s += wsI[k]; }
    }
}

__global__ __launch_bounds__(256) void scatter8(int* __restrict__ wsI) {
    const int b = blockIdx.x * 256 + threadIdx.x;
    const int e = wsI[16 + b];
    const int slot = atomicAdd(&wsI[8 + e], 1);
    wsI[16 + NB + slot] = b;
}

// Fused 3-layer MLP over one 16-row tile of one expert.
// LDS: 64 KiB, two 32 KiB regions. A holds xs (16 KiB used) then h1; B holds h0.
__global__ __launch_bounds__(256, 2) void mlp_fused(
    const float* __restrict__ x,
    const float* __restrict__ W0, const float* __restrict__ b0,
    const float* __restrict__ W1, const float* __restrict__ b1,
    const float* __restrict__ Wo, const float* __restrict__ bo,
    const int* __restrict__ wsI, float* __restrict__ out) {
    __shared__ float smem[16384];     // 64 KiB
    __shared__ int rows_s[TB];
    float* xsA = smem;                // [TB][ND]  (region A, first 16 KiB)
    float* h0B = smem + 8192;         // [TB][NH]  (region B)
    float* h1A = smem;                // [TB][NH]  (region A, overwrites xs after layer0)

    const int t = threadIdx.x;

    // bijective XCD-chunked swizzle (consecutive tiles -> same XCD for weight L2 reuse)
    const int nwg = gridDim.x;
    const int q = nwg >> 3, r = nwg & 7;
    const int xcd = blockIdx.x & 7, local = blockIdx.x >> 3;
    const int lb = (xcd < r ? xcd * (q + 1) : r * (q + 1) + (xcd - r) * q) + local;

    // map logical block -> (expert, tile)
    int e = -1, tile = 0, base = 0, cnt = 0;
    {
        int accT = 0, off = 0;
#pragma unroll
        for (int k = 0; k < NK; k++) {
            const int c = wsI[k];
            const int nt = (c + TB - 1) / TB;
            if (e < 0 && lb < accT + nt) { e = k; tile = lb - accT; base = off; cnt = c; }
            accT += nt; off += c;
        }
    }
    if (e < 0) return;

    const int* perm = wsI + 16 + NB;
    if (t < TB) {
        const int lr = tile * TB + t;
        rows_s[t] = (lr < cnt) ? perm[base + lr] : -1;
    }
    __syncthreads();

    // stage x rows (coalesced: each 256-thread sweep loads one full row)
    for (int i = t; i < TB * ND; i += 256) {
        const int rr = i >> 8;        // ND = 256
        const int d = i & (ND - 1);
        const int g = rows_s[rr];
        xsA[i] = (g >= 0) ? x[(size_t)g * ND + d] : 0.0f;
    }
    __syncthreads();

    const int c2 = t * 2;             // 2 contiguous output cols per thread (H=512)

    // ---------- layer 0: h0 = tanh(x @ W0[e] + b0[e]) ----------
    {
        const float* W0k = W0 + (size_t)e * ND * NH;
        float2 acc[TB];
#pragma unroll
        for (int rr = 0; rr < TB; rr++) acc[rr] = make_float2(0.f, 0.f);
        for (int d = 0; d < ND; d += 4) {
            const float2 w0 = *(const float2*)(W0k + (size_t)(d + 0) * NH + c2);
            const float2 w1 = *(const float2*)(W0k + (size_t)(d + 1) * NH + c2);
            const float2 w2 = *(const float2*)(W0k + (size_t)(d + 2) * NH + c2);
            const float2 w3 = *(const float2*)(W0k + (size_t)(d + 3) * NH + c2);
#pragma unroll
            for (int rr = 0; rr < TB; rr++) {
                const float4 xv = *(const float4*)(xsA + rr * ND + d);
                float ax = acc[rr].x, ay = acc[rr].y;
                ax = fmaf(xv.x, w0.x, ax); ay = fmaf(xv.x, w0.y, ay);
                ax = fmaf(xv.y, w1.x, ax); ay = fmaf(xv.y, w1.y, ay);
                ax = fmaf(xv.z, w2.x, ax); ay = fmaf(xv.z, w2.y, ay);
                ax = fmaf(xv.w, w3.x, ax); ay = fmaf(xv.w, w3.y, ay);
                acc[rr].x = ax; acc[rr].y = ay;
            }
        }
        const float2 bb = *(const float2*)(b0 + (size_t)e * NH + c2);
#pragma unroll
        for (int rr = 0; rr < TB; rr++) {
            h0B[rr * NH + c2]     = tanhf(acc[rr].x + bb.x);
            h0B[rr * NH + c2 + 1] = tanhf(acc[rr].y + bb.y);
        }
    }
    __syncthreads();

    // ---------- layer 1: h1 = tanh(h0 @ W1[e] + b1[e]) ----------
    {
        const float* W1k = W1 + (size_t)e * NH * NH;
        float2 acc[TB];
#pragma unroll
        for (int rr = 0; rr < TB; rr++) acc[rr] = make_float2(0.f, 0.f);
        for (int g = 0; g < NH; g += 4) {
            const float2 w0 = *(const float2*)(W1k + (size_t)(g + 0) * NH + c2);
            const float2 w1 = *(const float2*)(W1k + (size_t)(g + 1) * NH + c2);
            const float2 w2 = *(const float2*)(W1k + (size_t)(g + 2) * NH + c2);
            const float2 w3 = *(const float2*)(W1k + (size_t)(g + 3) * NH + c2);
#pragma unroll
            for (int rr = 0; rr < TB; rr++) {
                const float4 hv = *(const float4*)(h0B + rr * NH + g);
                float ax = acc[rr].x, ay = acc[rr].y;
                ax = fmaf(hv.x, w0.x, ax); ay = fmaf(hv.x, w0.y, ay);
                ax = fmaf(hv.y, w1.x, ax); ay = fmaf(hv.y, w1.y, ay);
                ax = fmaf(hv.z, w2.x, ax); ay = fmaf(hv.z, w2.y, ay);
                ax = fmaf(hv.w, w3.x, ax); ay = fmaf(hv.w, w3.y, ay);
                acc[rr].x = ax; acc[rr].y = ay;
            }
        }
        const float2 bb = *(const float2*)(b1 + (size_t)e * NH + c2);
        // region A free after layer0's barrier (nobody reads xs anymore)
#pragma unroll
        for (int rr = 0; rr < TB; rr++) {
            h1A[rr * NH + c2]     = tanhf(acc[rr].x + bb.x);
            h1A[rr * NH + c2 + 1] = tanhf(acc[rr].y + bb.y);
        }
    }
    __syncthreads();

    // ---------- layer 2: out = h1 @ Wo[e] + bo[e] ----------
    {
        const float* Wok = Wo + (size_t)e * NH * NO;
        const int col = t & (NO - 1);
        const int rg = t >> 6;        // 4 row-groups of 4 rows
        float a2[4] = {0.f, 0.f, 0.f, 0.f};
        for (int g = 0; g < NH; g += 4) {
            const float w0 = Wok[(size_t)(g + 0) * NO + col];
            const float w1 = Wok[(size_t)(g + 1) * NO + col];
            const float w2 = Wok[(size_t)(g + 2) * NO + col];
            const float w3 = Wok[(size_t)(g + 3) * NO + col];
#pragma unroll
            for (int j = 0; j < 4; j++) {
                const float4 hv = *(const float4*)(h1A + (rg * 4 + j) * NH + g);
                a2[j] = fmaf(hv.x, w0, fmaf(hv.y, w1, fmaf(hv.z, w2, fmaf(hv.w, w3, a2[j]))));
            }
        }
        const float bv = bo[(size_t)e * NO + col];
#pragma unroll
        for (int j = 0; j < 4; j++) {
            const int lr = rg * 4 + j;
            const int g = rows_s[lr];
            if (g >= 0) out[(size_t)g * NO + col] = a2[j] + bv;
        }
    }
}

extern "C" void kernel_launch(void* const* d_in, const int* in_sizes, int n_in,
                              void* d_out, int out_size, void* d_ws, size_t ws_size,
                              hipStream_t stream) {
    const float* x  = (const float*)d_in[0];
    const float* W0 = (const float*)d_in[1];
    const float* b0 = (const float*)d_in[2];
    const float* W1 = (const float*)d_in[3];
    const float* b1 = (const float*)d_in[4];
    const float* Wo = (const float*)d_in[5];
    const float* bo = (const float*)d_in[6];
    float* out = (float*)d_out;
    int* wsI = (int*)d_ws;

    hipMemsetAsync(wsI, 0, 16 * sizeof(int), stream);              // counts + cursor
    router_count<<<NB / 256, 256, 0, stream>>>(x, wsI);
    scan8<<<1, 64, 0, stream>>>(wsI);
    scatter8<<<NB / 256, 256, 0, stream>>>(wsI);
    const int ntiles_max = NB / TB + NK;                           // 520
    mlp_fused<<<ntiles_max, 256, 0, stream>>>(x, W0, b0, W1, b1, Wo, bo, wsI, out);
}

// Round 4
// 187.669 us; speedup vs baseline: 1.5951x; 1.5951x over previous
//
#include <hip/hip_runtime.h>

#define NB 8192
#define ND 256
#define NH 512
#define NO 64
#define NK 8
#define TB 16

typedef unsigned short u16;
using bf16x8 = __attribute__((ext_vector_type(8))) short;
using f32x4  = __attribute__((ext_vector_type(4))) float;

__device__ __forceinline__ u16 bf16rne(float f) {
    unsigned u = __float_as_uint(f);
    return (u16)((u + 0x7FFFu + ((u >> 16) & 1u)) >> 16);
}

__device__ __forceinline__ float fast_tanh(float v) {
    float a = fabsf(v);
    float e = __expf(-2.0f * a);
    float t = (1.0f - e) * __builtin_amdgcn_rcpf(1.0f + e);
    return copysignf(t, v);
}

// ws layout (bytes):
//   [0, 32)        : int cnt[8]
//   [64, 64+256KB) : int bucket[8][8192]
//   [512KB, +2MB)  : u16 W0T [8][512][256]   (bf16, [h][d])
//   [+2MB, +4MB)   : u16 W1T [8][512][512]   (bf16, [h_out][g_in])
//   [+6MB, +0.5MB) : u16 WoT [8][64][512]    (bf16, [o][g])

// ---------------- prep: weight transpose+bf16 (832 blocks) + router (32 blocks) ----------------
__global__ __launch_bounds__(256) void prep_kernel(
    const float* __restrict__ x,
    const float* __restrict__ W0, const float* __restrict__ W1, const float* __restrict__ Wo,
    int* __restrict__ wsI, u16* __restrict__ W0T, u16* __restrict__ W1T, u16* __restrict__ WoT) {
    const int bid = blockIdx.x, t = threadIdx.x;
    if (bid >= 832) {                       // router: 32 blocks x 256 = 8192 rows
        const int b = (bid - 832) * 256 + t;
        const float v = x[(size_t)b * ND + 7];
        const int e = ((int)fabsf(v * 100.0f)) & (NK - 1);
        const int slot = atomicAdd(&wsI[e], 1);
        wsI[16 + e * NB + slot] = b;
        return;
    }
    __shared__ u16 tile[64][72];            // +8 pad
    const float* src; u16* dst; int R, C, r0, c0;
    if (bid < 256) {        // W0: R=256(d) x C=512(h), 4x8 tiles/expert
        int e = bid >> 5, tt = bid & 31; R = ND; C = NH;
        src = W0 + (size_t)e * ND * NH; dst = W0T + (size_t)e * NH * ND;
        r0 = (tt >> 3) * 64; c0 = (tt & 7) * 64;
    } else if (bid < 768) { // W1: 512x512, 8x8 tiles/expert
        int i = bid - 256; int e = i >> 6, tt = i & 63; R = NH; C = NH;
        src = W1 + (size_t)e * NH * NH; dst = W1T + (size_t)e * NH * NH;
        r0 = (tt >> 3) * 64; c0 = (tt & 7) * 64;
    } else {                // Wo: 512x64, 8x1 tiles/expert
        int i = bid - 768; int e = i >> 3, tt = i & 7; R = NH; C = NO;
        src = Wo + (size_t)e * NH * NO; dst = WoT + (size_t)e * NO * NH;
        r0 = tt * 64; c0 = 0;
    }
    {   // read 64x64 f32 coalesced, cvt bf16, stage LDS
        const int r = t >> 2, cc = (t & 3) * 16;
        const float* p = src + (size_t)(r0 + r) * C + c0 + cc;
#pragma unroll
        for (int j = 0; j < 16; j += 4) {
            float4 v = *(const float4*)(p + j);
            u16* q = &tile[r][cc + j];
            q[0] = bf16rne(v.x); q[1] = bf16rne(v.y); q[2] = bf16rne(v.z); q[3] = bf16rne(v.w);
        }
    }
    __syncthreads();
    {   // write transposed, coalesced
        const int oc = t >> 2, rr = (t & 3) * 16;
        u16* q = dst + (size_t)(c0 + oc) * R + r0 + rr;
#pragma unroll
        for (int j = 0; j < 16; j += 4) {
            ushort4 u;
            u.x = tile[rr + j + 0][oc]; u.y = tile[rr + j + 1][oc];
            u.z = tile[rr + j + 2][oc]; u.w = tile[rr + j + 3][oc];
            *(ushort4*)(q + j) = u;
        }
    }
}

// ---------------- fused MLP: 16 rows/block, 4 waves, MFMA 16x16x32 bf16 ----------------
// LDS byte map (65536 B): xshi[16][256]@0 (rowstride 512B), xslo@8192,
//   h0hi[16][512]@16384 (rowstride 1024B), h0lo@32768, h1hi@0 (alias xs), h1lo@49152.
// All planes XOR-swizzled: byte_in_row ^= (row&7)<<4  (T2; breaks the 16-way conflict).
__global__ __launch_bounds__(256, 2) void mlp_kernel(
    const float* __restrict__ x,
    const float* __restrict__ b0, const float* __restrict__ b1, const float* __restrict__ bo,
    const int* __restrict__ wsI,
    const u16* __restrict__ W0T, const u16* __restrict__ W1T, const u16* __restrict__ WoT,
    float* __restrict__ out) {
    const int e = blockIdx.x & (NK - 1);     // expert -> XCD pinning (round-robin dispatch)
    const int tile = blockIdx.x >> 3;
    const int cnt = wsI[e];
    if (tile * TB >= cnt) return;

    __shared__ u16 L[32768];
    __shared__ int rows_s[TB];
    const int t = threadIdx.x;
    const int* bucket = wsI + 16 + e * NB;
    if (t < TB) {
        int lr = tile * TB + t;
        rows_s[t] = (lr < cnt) ? bucket[lr] : -1;
    }
    __syncthreads();

    // ---- stage x rows: f32 -> hi(trunc)/lo(rne) planes ----
#pragma unroll
    for (int s = 0; s < 4; ++s) {
        int i = t + s * 256;                 // float4 index; 64 per row
        int row = i >> 6, d4 = i & 63;
        int g = rows_s[row];
        float4 v = (g >= 0) ? *(const float4*)(x + (size_t)g * ND + d4 * 4)
                            : make_float4(0.f, 0.f, 0.f, 0.f);
        ushort4 hi, lo;
        unsigned ux;
        ux = __float_as_uint(v.x); hi.x = ux >> 16; lo.x = bf16rne(v.x - __uint_as_float(ux & 0xFFFF0000u));
        ux = __float_as_uint(v.y); hi.y = ux >> 16; lo.y = bf16rne(v.y - __uint_as_float(ux & 0xFFFF0000u));
        ux = __float_as_uint(v.z); hi.z = ux >> 16; lo.z = bf16rne(v.z - __uint_as_float(ux & 0xFFFF0000u));
        ux = __float_as_uint(v.w); hi.w = ux >> 16; lo.w = bf16rne(v.w - __uint_as_float(ux & 0xFFFF0000u));
        int bb = (row * 512 + d4 * 8) ^ ((row & 7) << 4);
        *(ushort4*)&L[bb >> 1] = hi;
        *(ushort4*)&L[(bb + 8192) >> 1] = lo;
    }
    __syncthreads();

    const int wid = t >> 6, l = t & 63;
    const int lrow = l & 15;                 // A-row / B-col within 16-tile
    const int lk = (l >> 4) * 8;             // k-offset of this lane's 8 contiguous k

    f32x4 acc[8];
#pragma unroll
    for (int j = 0; j < 8; ++j) acc[j] = (f32x4){0.f, 0.f, 0.f, 0.f};

    // ---- layer 0: h0 = tanh(x @ W0 + b0), K=256, 32 n-tiles (8/wave) ----
    {
        const u16* W0e = W0T + (size_t)e * NH * ND;
        for (int ks = 0; ks < ND; ks += 32) {
            int ab = (lrow * 512 + (((ks + lk) * 2) ^ ((lrow & 7) << 4)));
            bf16x8 ahi = *(const bf16x8*)&L[ab >> 1];
            bf16x8 alo = *(const bf16x8*)&L[(ab + 8192) >> 1];
#pragma unroll
            for (int j = 0; j < 8; ++j) {
                int n = wid * 8 + j;
                bf16x8 bf = *(const bf16x8*)(W0e + (size_t)(n * 16 + lrow) * ND + ks + lk);
                acc[j] = __builtin_amdgcn_mfma_f32_16x16x32_bf16(ahi, bf, acc[j], 0, 0, 0);
                acc[j] = __builtin_amdgcn_mfma_f32_16x16x32_bf16(alo, bf, acc[j], 0, 0, 0);
            }
        }
#pragma unroll
        for (int j = 0; j < 8; ++j) {
            int col = (wid * 8 + j) * 16 + lrow;
            float bias = b0[e * NH + col];
#pragma unroll
            for (int r = 0; r < 4; ++r) {
                int row = (l >> 4) * 4 + r;
                float tv = fast_tanh(acc[j][r] + bias);
                unsigned u = __float_as_uint(tv);
                int bb = row * 1024 + ((col * 2) ^ ((row & 7) << 4));
                L[(16384 + bb) >> 1] = (u16)(u >> 16);
                L[(32768 + bb) >> 1] = bf16rne(tv - __uint_as_float(u & 0xFFFF0000u));
            }
        }
    }
    __syncthreads();

    // ---- layer 1: h1 = tanh(h0 @ W1 + b1), K=512 ----
    {
#pragma unroll
        for (int j = 0; j < 8; ++j) acc[j] = (f32x4){0.f, 0.f, 0.f, 0.f};
        const u16* W1e = W1T + (size_t)e * NH * NH;
        for (int ks = 0; ks < NH; ks += 32) {
            int ab = lrow * 1024 + (((ks + lk) * 2) ^ ((lrow & 7) << 4));
            bf16x8 ahi = *(const bf16x8*)&L[(16384 + ab) >> 1];
            bf16x8 alo = *(const bf16x8*)&L[(32768 + ab) >> 1];
#pragma unroll
            for (int j = 0; j < 8; ++j) {
                int n = wid * 8 + j;
                bf16x8 bf = *(const bf16x8*)(W1e + (size_t)(n * 16 + lrow) * NH + ks + lk);
                acc[j] = __builtin_amdgcn_mfma_f32_16x16x32_bf16(ahi, bf, acc[j], 0, 0, 0);
                acc[j] = __builtin_amdgcn_mfma_f32_16x16x32_bf16(alo, bf, acc[j], 0, 0, 0);
            }
        }
#pragma unroll
        for (int j = 0; j < 8; ++j) {
            int col = (wid * 8 + j) * 16 + lrow;
            float bias = b1[e * NH + col];
#pragma unroll
            for (int r = 0; r < 4; ++r) {
                int row = (l >> 4) * 4 + r;
                float tv = fast_tanh(acc[j][r] + bias);
                unsigned u = __float_as_uint(tv);
                int bb = row * 1024 + ((col * 2) ^ ((row & 7) << 4));
                L[(0 + bb) >> 1] = (u16)(u >> 16);              // h1hi over xs (dead)
                L[(49152 + bb) >> 1] = bf16rne(tv - __uint_as_float(u & 0xFFFF0000u));
            }
        }
    }
    __syncthreads();

    // ---- layer 2: out = h1 @ Wo + bo, K=512, N=64 (1 n-tile/wave) ----
    {
        const u16* Woe = WoT + (size_t)e * NO * NH;
        f32x4 a2 = (f32x4){0.f, 0.f, 0.f, 0.f};
        for (int ks = 0; ks < NH; ks += 32) {
            int ab = lrow * 1024 + (((ks + lk) * 2) ^ ((lrow & 7) << 4));
            bf16x8 ahi = *(const bf16x8*)&L[ab >> 1];
            bf16x8 alo = *(const bf16x8*)&L[(49152 + ab) >> 1];
            bf16x8 bf = *(const bf16x8*)(Woe + (size_t)(wid * 16 + lrow) * NH + ks + lk);
            a2 = __builtin_amdgcn_mfma_f32_16x16x32_bf16(ahi, bf, a2, 0, 0, 0);
            a2 = __builtin_amdgcn_mfma_f32_16x16x32_bf16(alo, bf, a2, 0, 0, 0);
        }
        int col = wid * 16 + lrow;
        float bias = bo[e * NO + col];
#pragma unroll
        for (int r = 0; r < 4; ++r) {
            int row = (l >> 4) * 4 + r;
            int g = rows_s[row];
            if (g >= 0) out[(size_t)g * NO + col] = a2[r] + bias;
        }
    }
}

extern "C" void kernel_launch(void* const* d_in, const int* in_sizes, int n_in,
                              void* d_out, int out_size, void* d_ws, size_t ws_size,
                              hipStream_t stream) {
    const float* x  = (const float*)d_in[0];
    const float* W0 = (const float*)d_in[1];
    const float* b0 = (const float*)d_in[2];
    const float* W1 = (const float*)d_in[3];
    const float* b1 = (const float*)d_in[4];
    const float* Wo = (const float*)d_in[5];
    const float* bo = (const float*)d_in[6];
    float* out = (float*)d_out;
    int* wsI = (int*)d_ws;
    u16* W0T = (u16*)((char*)d_ws + (512 << 10));
    u16* W1T = W0T + (size_t)NK * NH * ND;
    u16* WoT = W1T + (size_t)NK * NH * NH;

    hipMemsetAsync(wsI, 0, 64, stream);     // counts
    prep_kernel<<<864, 256, 0, stream>>>(x, W0, W1, Wo, wsI, W0T, W1T, WoT);
    mlp_kernel<<<NK * (NB / TB), 256, 0, stream>>>(x, b0, b1, bo, wsI, W0T, W1T, WoT, out);
}

// Round 5
// 103.180 us; speedup vs baseline: 2.9013x; 1.8188x over previous
//
#include <hip/hip_runtime.h>

#define NB 8192
#define ND 256
#define NH 512
#define NO 64
#define NK 8
#define TB 32

typedef unsigned short u16;
using bf16x8 = __attribute__((ext_vector_type(8))) short;
using u16x8  = __attribute__((ext_vector_type(8))) unsigned short;
using f32x4  = __attribute__((ext_vector_type(4))) float;

__device__ __forceinline__ u16 bf16rne(float f) {
    unsigned u = __float_as_uint(f);
    return (u16)((u + 0x7FFFu + ((u >> 16) & 1u)) >> 16);
}

__device__ __forceinline__ float fast_tanh(float v) {
    float a = fabsf(v);
    float e = __expf(-2.0f * a);
    float t = (1.0f - e) * __builtin_amdgcn_rcpf(1.0f + e);
    return copysignf(t, v);
}

// ws layout (bytes):
//   [0, 32)        : int cnt[8]            (memset to 0 each call)
//   [64, ~256KB)   : int bucket[8][8192]
//   [0.5MB, 2.5MB) : u16 W0F[8][8][32][64][8]   fragment-packed: [kt][nt][lane][8k]
//   [2.5MB, 6.5MB) : u16 W1F[8][16][32][64][8]
//   [6.5MB, 7.0MB) : u16 WoF[8][16][4][64][8]
// Fragment (kt,nt,lane,i): weight element W[k = kt*32 + (lane>>4)*8 + i][n = nt*16 + (lane&15)]
// -> every wave B-load is 64 lanes x 16B CONTIGUOUS (1KB, single transaction burst).

__global__ __launch_bounds__(256) void prep_kernel(
    const float* __restrict__ x,
    const float* __restrict__ W0, const float* __restrict__ W1, const float* __restrict__ Wo,
    int* __restrict__ wsI, u16* __restrict__ W0F, u16* __restrict__ W1F, u16* __restrict__ WoF) {
    const int bid = blockIdx.x, t = threadIdx.x;
    if (bid >= 832) {                        // router: 32 blocks x 256
        __shared__ int lc[NK], lbase[NK];
        if (t < NK) lc[t] = 0;
        __syncthreads();
        const int b = (bid - 832) * 256 + t;
        const float v = x[(size_t)b * ND + 7];
        const int e = ((int)fabsf(v * 100.0f)) & (NK - 1);
        const int slot = atomicAdd(&lc[e], 1);          // LDS atomic
        __syncthreads();
        if (t < NK) lbase[t] = atomicAdd(&wsI[t], lc[t]); // 8 global atomics/block
        __syncthreads();
        wsI[16 + e * NB + lbase[e] + slot] = b;
        return;
    }
    // weight fragment-packing: one 64x64 (k x n) macro-tile per block
    __shared__ u16 tile[64][76];             // 152B row stride: 8B-aligned, low conflicts
    const float* src; u16* dst; int C, NT, r0, c0;
    if (bid < 256) {         // W0: K=256, N=512 -> 4x8 macro-tiles/expert
        int e = bid >> 5, tt = bid & 31; C = NH; NT = 32;
        src = W0 + (size_t)e * ND * NH; dst = W0F + (size_t)e * ND * NH;
        r0 = (tt >> 3) * 64; c0 = (tt & 7) * 64;
    } else if (bid < 768) {  // W1: K=512, N=512 -> 8x8
        int i = bid - 256, e = i >> 6, tt = i & 63; C = NH; NT = 32;
        src = W1 + (size_t)e * NH * NH; dst = W1F + (size_t)e * NH * NH;
        r0 = (tt >> 3) * 64; c0 = (tt & 7) * 64;
    } else {                 // Wo: K=512, N=64 -> 8x1
        int i = bid - 768, e = i >> 3, tt = i & 7; C = NO; NT = 4;
        src = Wo + (size_t)e * NH * NO; dst = WoF + (size_t)e * NH * NO;
        r0 = tt * 64; c0 = 0;
    }
    {   // read 64 k-rows x 64 n-cols f32 coalesced, cvt bf16, stage LDS
        const int r = t >> 2, cc = (t & 3) * 16;
        const float* p = src + (size_t)(r0 + r) * C + c0 + cc;
#pragma unroll
        for (int j = 0; j < 16; j += 4) {
            float4 v = *(const float4*)(p + j);
            ushort4 h;
            h.x = bf16rne(v.x); h.y = bf16rne(v.y); h.z = bf16rne(v.z); h.w = bf16rne(v.w);
            *(ushort4*)&tile[r][cc + j] = h;
        }
    }
    __syncthreads();
    {   // emit 512 fragments (16B each), wave-contiguous global stores
#pragma unroll
        for (int i = 0; i < 2; ++i) {
            const int f = t + i * 256;
            const int lane = f & 63, s = f >> 6;
            const int ktl = s >> 2, ntl = s & 3;
            const int kt = (r0 >> 5) + ktl, nt = (c0 >> 4) + ntl;
            const int kloc = ktl * 32 + (lane >> 4) * 8, nloc = ntl * 16 + (lane & 15);
            u16x8 fr;
#pragma unroll
            for (int q = 0; q < 8; ++q) fr[q] = tile[kloc + q][nloc];
            *(u16x8*)(dst + (size_t)(((kt * NT + nt) << 6) + lane) * 8) = fr;
        }
    }
}

// ---------------- fused MLP: 32 rows/block, 8 waves, single-plane bf16, MFMA 16x16x32 ----------------
// LDS 64KB: bytes [0,32K) = xs (16KB, dead after L0) then h1 (32KB, written L1-epilogue);
//           bytes [32K,64K) = h0. All planes XOR-swizzled: byte_in_row ^= (row&7)<<4.
__global__ __launch_bounds__(512, 4) void mlp_kernel(
    const float* __restrict__ x,
    const float* __restrict__ b0, const float* __restrict__ b1, const float* __restrict__ bo,
    const int* __restrict__ wsI,
    const u16* __restrict__ W0F, const u16* __restrict__ W1F, const u16* __restrict__ WoF,
    float* __restrict__ out) {
    const int e = blockIdx.x & (NK - 1);     // expert -> XCD pinning
    const int tile = blockIdx.x >> 3;
    const int cnt = wsI[e];
    if (tile * TB >= cnt) return;

    __shared__ u16 L[32768];                 // 64KB
    __shared__ int rows_s[TB];
    const int t = threadIdx.x;
    const int* bucket = wsI + 16 + e * NB;
    if (t < TB) {
        int lr = tile * TB + t;
        rows_s[t] = (lr < cnt) ? bucket[lr] : -1;
    }
    __syncthreads();

    // ---- stage x rows -> bf16 plane [32][256], row stride 512B ----
#pragma unroll
    for (int s = 0; s < 4; ++s) {
        int i = t + s * 512;                 // float4 index, 64 per row
        int row = i >> 6, d4 = i & 63;
        int g = rows_s[row];
        float4 v = (g >= 0) ? *(const float4*)(x + (size_t)g * ND + d4 * 4)
                            : make_float4(0.f, 0.f, 0.f, 0.f);
        ushort4 h;
        h.x = bf16rne(v.x); h.y = bf16rne(v.y); h.z = bf16rne(v.z); h.w = bf16rne(v.w);
        int bb = (row * 512 + d4 * 8) ^ ((row & 7) << 4);
        *(ushort4*)&L[bb >> 1] = h;
    }
    __syncthreads();

    const int wid = t >> 6, l = t & 63;
    const int lrow = l & 15;                 // m-row / n-col within 16-tile
    const int lkb = (l >> 4) * 16;           // byte offset of lane's 8-k chunk
    const int swz = (lrow & 7) << 4;

    f32x4 acc[2][4];
#pragma unroll
    for (int m = 0; m < 2; ++m)
#pragma unroll
        for (int j = 0; j < 4; ++j) acc[m][j] = (f32x4){0.f, 0.f, 0.f, 0.f};

    // ---- layer 0: h0 = tanh(x @ W0 + b0), K=256 (KT=8), wave owns nt = wid*4+j ----
    {
        const u16* P = W0F + (size_t)e * ND * NH + ((wid * 4) * 64 + l) * 8;
        bf16x8 cA[4], cB[4];
#pragma unroll
        for (int j = 0; j < 4; ++j) cA[j] = *(const bf16x8*)(P + j * 512);
#pragma unroll
        for (int kt = 0; kt < 8; kt += 2) {
#pragma unroll
            for (int j = 0; j < 4; ++j) cB[j] = *(const bf16x8*)(P + ((kt + 1) * 32 + j) * 512);
            {
                int kb = kt * 64;
                bf16x8 a0 = *(const bf16x8*)&L[((0 * 16 + lrow) * 512 + ((kb + lkb) ^ swz)) >> 1];
                bf16x8 a1 = *(const bf16x8*)&L[((1 * 16 + lrow) * 512 + ((kb + lkb) ^ swz)) >> 1];
#pragma unroll
                for (int j = 0; j < 4; ++j) {
                    acc[0][j] = __builtin_amdgcn_mfma_f32_16x16x32_bf16(a0, cA[j], acc[0][j], 0, 0, 0);
                    acc[1][j] = __builtin_amdgcn_mfma_f32_16x16x32_bf16(a1, cA[j], acc[1][j], 0, 0, 0);
                }
            }
            if (kt + 2 < 8) {
#pragma unroll
                for (int j = 0; j < 4; ++j) cA[j] = *(const bf16x8*)(P + ((kt + 2) * 32 + j) * 512);
            }
            {
                int kb = (kt + 1) * 64;
                bf16x8 a0 = *(const bf16x8*)&L[((0 * 16 + lrow) * 512 + ((kb + lkb) ^ swz)) >> 1];
                bf16x8 a1 = *(const bf16x8*)&L[((1 * 16 + lrow) * 512 + ((kb + lkb) ^ swz)) >> 1];
#pragma unroll
                for (int j = 0; j < 4; ++j) {
                    acc[0][j] = __builtin_amdgcn_mfma_f32_16x16x32_bf16(a0, cB[j], acc[0][j], 0, 0, 0);
                    acc[1][j] = __builtin_amdgcn_mfma_f32_16x16x32_bf16(a1, cB[j], acc[1][j], 0, 0, 0);
                }
            }
        }
        // epilogue -> h0 @ byte 32768, row stride 1024B
#pragma unroll
        for (int m = 0; m < 2; ++m)
#pragma unroll
            for (int j = 0; j < 4; ++j) {
                int col = (wid * 4 + j) * 16 + lrow;
                float bias = b0[e * NH + col];
#pragma unroll
                for (int r = 0; r < 4; ++r) {
                    int row = m * 16 + (l >> 4) * 4 + r;
                    float tv = fast_tanh(acc[m][j][r] + bias);
                    int bb = 32768 + row * 1024 + ((col * 2) ^ ((row & 7) << 4));
                    L[bb >> 1] = bf16rne(tv);
                }
            }
    }
    __syncthreads();

    // ---- layer 1: h1 = tanh(h0 @ W1 + b1), K=512 (KT=16) ----
    {
#pragma unroll
        for (int m = 0; m < 2; ++m)
#pragma unroll
            for (int j = 0; j < 4; ++j) acc[m][j] = (f32x4){0.f, 0.f, 0.f, 0.f};
        const u16* P = W1F + (size_t)e * NH * NH + ((wid * 4) * 64 + l) * 8;
        bf16x8 cA[4], cB[4];
#pragma unroll
        for (int j = 0; j < 4; ++j) cA[j] = *(const bf16x8*)(P + j * 512);
#pragma unroll
        for (int kt = 0; kt < 16; kt += 2) {
#pragma unroll
            for (int j = 0; j < 4; ++j) cB[j] = *(const bf16x8*)(P + ((kt + 1) * 32 + j) * 512);
            {
                int kb = 32768 + (kt * 64 + lkb);
                bf16x8 a0 = *(const bf16x8*)&L[((0 * 16 + lrow) * 1024 + 32768 + ((kt * 64 + lkb) ^ swz)) >> 1];
                bf16x8 a1 = *(const bf16x8*)&L[((1 * 16 + lrow) * 1024 + 32768 + ((kt * 64 + lkb) ^ swz)) >> 1];
                (void)kb;
#pragma unroll
                for (int j = 0; j < 4; ++j) {
                    acc[0][j] = __builtin_amdgcn_mfma_f32_16x16x32_bf16(a0, cA[j], acc[0][j], 0, 0, 0);
                    acc[1][j] = __builtin_amdgcn_mfma_f32_16x16x32_bf16(a1, cA[j], acc[1][j], 0, 0, 0);
                }
            }
            if (kt + 2 < 16) {
#pragma unroll
                for (int j = 0; j < 4; ++j) cA[j] = *(const bf16x8*)(P + ((kt + 2) * 32 + j) * 512);
            }
            {
                bf16x8 a0 = *(const bf16x8*)&L[((0 * 16 + lrow) * 1024 + 32768 + (((kt + 1) * 64 + lkb) ^ swz)) >> 1];
                bf16x8 a1 = *(const bf16x8*)&L[((1 * 16 + lrow) * 1024 + 32768 + (((kt + 1) * 64 + lkb) ^ swz)) >> 1];
#pragma unroll
                for (int j = 0; j < 4; ++j) {
                    acc[0][j] = __builtin_amdgcn_mfma_f32_16x16x32_bf16(a0, cB[j], acc[0][j], 0, 0, 0);
                    acc[1][j] = __builtin_amdgcn_mfma_f32_16x16x32_bf16(a1, cB[j], acc[1][j], 0, 0, 0);
                }
            }
        }
        // epilogue -> h1 @ byte 0 (over dead xs), row stride 1024B
#pragma unroll
        for (int m = 0; m < 2; ++m)
#pragma unroll
            for (int j = 0; j < 4; ++j) {
                int col = (wid * 4 + j) * 16 + lrow;
                float bias = b1[e * NH + col];
#pragma unroll
                for (int r = 0; r < 4; ++r) {
                    int row = m * 16 + (l >> 4) * 4 + r;
                    float tv = fast_tanh(acc[m][j][r] + bias);
                    int bb = row * 1024 + ((col * 2) ^ ((row & 7) << 4));
                    L[bb >> 1] = bf16rne(tv);
                }
            }
    }
    __syncthreads();

    // ---- layer 2: out = h1 @ Wo + bo, K=512 (KT=16); wave -> (nt = wid&3, mt = wid>>2) ----
    {
        const int nt = wid & 3, mt = wid >> 2;
        const u16* P = WoF + (size_t)e * NH * NO + (nt * 64 + l) * 8;
        f32x4 a2 = (f32x4){0.f, 0.f, 0.f, 0.f};
        bf16x8 wA = *(const bf16x8*)(P);
#pragma unroll
        for (int kt = 0; kt < 16; kt += 2) {
            bf16x8 wB = *(const bf16x8*)(P + ((kt + 1) * 4) * 512);
            {
                bf16x8 a = *(const bf16x8*)&L[((mt * 16 + lrow) * 1024 + ((kt * 64 + lkb) ^ swz)) >> 1];
                a2 = __builtin_amdgcn_mfma_f32_16x16x32_bf16(a, wA, a2, 0, 0, 0);
            }
            if (kt + 2 < 16) wA = *(const bf16x8*)(P + ((kt + 2) * 4) * 512);
            {
                bf16x8 a = *(const bf16x8*)&L[((mt * 16 + lrow) * 1024 + (((kt + 1) * 64 + lkb) ^ swz)) >> 1];
                a2 = __builtin_amdgcn_mfma_f32_16x16x32_bf16(a, wB, a2, 0, 0, 0);
            }
        }
        int col = nt * 16 + lrow;
        float bias = bo[e * NO + col];
#pragma unroll
        for (int r = 0; r < 4; ++r) {
            int row = mt * 16 + (l >> 4) * 4 + r;
            int g = rows_s[row];
            if (g >= 0) out[(size_t)g * NO + col] = a2[r] + bias;
        }
    }
}

extern "C" void kernel_launch(void* const* d_in, const int* in_sizes, int n_in,
                              void* d_out, int out_size, void* d_ws, size_t ws_size,
                              hipStream_t stream) {
    const float* x  = (const float*)d_in[0];
    const float* W0 = (const float*)d_in[1];
    const float* b0 = (const float*)d_in[2];
    const float* W1 = (const float*)d_in[3];
    const float* b1 = (const float*)d_in[4];
    const float* Wo = (const float*)d_in[5];
    const float* bo = (const float*)d_in[6];
    float* out = (float*)d_out;
    int* wsI = (int*)d_ws;
    u16* W0F = (u16*)((char*)d_ws + (512 << 10));
    u16* W1F = W0F + (size_t)NK * ND * NH;
    u16* WoF = W1F + (size_t)NK * NH * NH;

    hipMemsetAsync(wsI, 0, 64, stream);     // counts
    prep_kernel<<<864, 256, 0, stream>>>(x, W0, W1, Wo, wsI, W0F, W1F, WoF);
    mlp_kernel<<<NK * (NB / TB), 512, 0, stream>>>(x, b0, b1, bo, wsI, W0F, W1F, WoF, out);
}